// Round 14
// baseline (678.636 us; speedup 1.0000x reference)
//
#include <hip/hip_runtime.h>
#include <hip/hip_bf16.h>
#include <hip/hip_fp16.h>
#include <math.h>

typedef __hip_bfloat16 bf16;
typedef __attribute__((ext_vector_type(8))) short short8;   // 8 bf16 / 8 f16 (16 B)
typedef __attribute__((ext_vector_type(4))) float f32x4;    // MFMA C/D frag

union UB { short8 v; bf16 e[8]; };
union UH { short8 v; __half e[8]; };

// ---------------- helpers ----------------
__device__ __forceinline__ float wred(float v) {
  #pragma unroll
  for (int o = 32; o > 0; o >>= 1) v += __shfl_xor(v, o, 64);
  return v;
}
__device__ __forceinline__ float sigf(float x) { return 1.f / (1.f + expf(-x)); }

__device__ __forceinline__ void gl_lds16(const bf16* g, const bf16* lds) {
  __builtin_amdgcn_global_load_lds((const __attribute__((address_space(1))) void*)g,
                                   (__attribute__((address_space(3))) void*)lds,
                                   16, 0, 0);
}
__device__ __forceinline__ f32x4 mfma16(short8 a, short8 b, f32x4 c) {
  return __builtin_amdgcn_mfma_f32_16x16x32_bf16(a, b, c, 0, 0, 0);
}

// ---- merged batch GEMM: xzrp + xcp, K=512, vector epi + NT stores ----
__global__ __launch_bounds__(256, 2)
void gemmx(const bf16* __restrict__ A, const bf16* __restrict__ Wxzrt,
           const bf16* __restrict__ Wxct, const float* __restrict__ b_zr,
           const float* __restrict__ b_c, bf16* __restrict__ xzrp,
           bf16* __restrict__ xcp)
{
  __shared__ __align__(16) char smem[34816];
  bf16* As = (bf16*)smem;
  bf16* Bs = (bf16*)(smem + 16384);
  __half* Ts = (__half*)smem;

  const int tid  = threadIdx.x;
  const int wave = tid >> 6, lane = tid & 63;
  const int lm = lane & 15, q = lane >> 4;
  const int brow = blockIdx.x, bcol = blockIdx.y;   // XCD-local brow
  const int wr = (wave >> 1) * 64, wc = (wave & 1) * 64;
  const int srow = lane >> 3, sslot = lane & 7;

  const bf16* Bt; const float* bias; bf16* C; int ldc, colbase;
  if (bcol < 8) { Bt = Wxzrt + (size_t)bcol * 128 * 512; bias = b_zr; C = xzrp; ldc = 1024; colbase = bcol * 128; }
  else          { Bt = Wxct + (size_t)(bcol - 8) * 128 * 512; bias = b_c; C = xcp; ldc = 512; colbase = (bcol - 8) * 128; }

  f32x4 acc[4][4];
  #pragma unroll
  for (int i = 0; i < 4; ++i)
    #pragma unroll
    for (int j = 0; j < 4; ++j) acc[i][j] = (f32x4){0.f, 0.f, 0.f, 0.f};

  for (int kb = 0; kb < 512; kb += 64) {
    #pragma unroll
    for (int j = 0; j < 4; ++j) {
      int ml = wave * 32 + j * 8 + srow;
      int cg = sslot ^ (ml & 7);
      gl_lds16(A + (size_t)(brow * 128 + ml) * 512 + kb + cg * 8, As + (wave * 4 + j) * 512);
      gl_lds16(Bt + (size_t)ml * 512 + kb + cg * 8, Bs + (wave * 4 + j) * 512);
    }
    __syncthreads();
    #pragma unroll
    for (int ks = 0; ks < 2; ++ks) {
      short8 af[4], bfr[4];
      #pragma unroll
      for (int i = 0; i < 4; ++i) {
        int cg = ks * 4 + q;
        int ml = wr + i * 16 + lm;
        af[i]  = *(const short8*)(As + ml * 64 + ((cg ^ (ml & 7)) * 8));
        int nl = wc + i * 16 + lm;
        bfr[i] = *(const short8*)(Bs + nl * 64 + ((cg ^ (nl & 7)) * 8));
      }
      #pragma unroll
      for (int i = 0; i < 4; ++i)
        #pragma unroll
        for (int j = 0; j < 4; ++j)
          acc[i][j] = mfma16(af[i], bfr[j], acc[i][j]);
    }
    __syncthreads();
  }
  #pragma unroll
  for (int i = 0; i < 4; ++i)
    #pragma unroll
    for (int j = 0; j < 4; ++j) {
      int col = wc + j * 16 + lm;
      float bv = bias[colbase + col];
      #pragma unroll
      for (int p = 0; p < 4; ++p)
        Ts[(wr + i * 16 + q * 4 + p) * 136 + col] = __float2half(acc[i][j][p] + bv);
    }
  __syncthreads();
  int row = tid >> 1, half = tid & 1;
  size_t grow = (size_t)(brow * 128 + row);
  #pragma unroll
  for (int v = 0; v < 8; ++v) {
    int col = half * 64 + v * 8;
    UH t; t.v = *(const short8*)(Ts + row * 136 + col);
    UB o;
    #pragma unroll
    for (int e = 0; e < 8; ++e) o.e[e] = __float2bfloat16(__half2float(t.e[e]));
    __builtin_nontemporal_store(o.v, (short8*)(C + grow * ldc + colbase + col));
  }
}

// ---- GCN batch GEMM: grid (256, 2, 2), brow fastest, NT stores ----
__global__ __launch_bounds__(256, 2)
void gcnk(const float* __restrict__ Ag, const float* __restrict__ Agi,
          const bf16* __restrict__ Wgt, const float* __restrict__ bias,
          bf16* __restrict__ out)
{
  __shared__ __align__(16) char smem[34816];
  bf16* As = (bf16*)smem;
  bf16* Bs = (bf16*)(smem + 16384);
  __half* Ts = (__half*)smem;

  const int tid  = threadIdx.x;
  const int wave = tid >> 6, lane = tid & 63;
  const int lm = lane & 15, q = lane >> 4;
  const int brow = blockIdx.x, bcol = blockIdx.y;
  const int z = blockIdx.z, cout = z * 256;
  const float* A = z ? Agi : Ag;
  const int wr = (wave >> 1) * 64, wc = (wave & 1) * 64;
  const int srow = lane >> 3, sslot = lane & 7;

  f32x4 acc[4][4];
  #pragma unroll
  for (int i = 0; i < 4; ++i)
    #pragma unroll
    for (int j = 0; j < 4; ++j) acc[i][j] = (f32x4){0.f, 0.f, 0.f, 0.f};

  for (int kb = 0; kb < 128; kb += 64) {
    #pragma unroll
    for (int j = 0; j < 4; ++j) {
      int ml = wave * 32 + j * 8 + srow;
      int cg = sslot ^ (ml & 7);
      const float* src = A + (size_t)(brow * 128 + ml) * 128 + kb + cg * 8;
      bf16 tmp[8];
      #pragma unroll
      for (int e = 0; e < 8; ++e) tmp[e] = __float2bfloat16(src[e]);
      *(short8*)(As + ml * 64 + sslot * 8) = *(const short8*)tmp;
      gl_lds16(Wgt + (size_t)(bcol * 128 + ml) * 128 + kb + cg * 8,   // no cout!
               Bs + (wave * 4 + j) * 512);
    }
    __syncthreads();
    #pragma unroll
    for (int ks = 0; ks < 2; ++ks) {
      short8 af[4], bfr[4];
      #pragma unroll
      for (int i = 0; i < 4; ++i) {
        int cg = ks * 4 + q;
        int ml = wr + i * 16 + lm;
        af[i]  = *(const short8*)(As + ml * 64 + ((cg ^ (ml & 7)) * 8));
        int nl = wc + i * 16 + lm;
        bfr[i] = *(const short8*)(Bs + nl * 64 + ((cg ^ (nl & 7)) * 8));
      }
      #pragma unroll
      for (int i = 0; i < 4; ++i)
        #pragma unroll
        for (int j = 0; j < 4; ++j)
          acc[i][j] = mfma16(af[i], bfr[j], acc[i][j]);
    }
    __syncthreads();
  }
  #pragma unroll
  for (int i = 0; i < 4; ++i)
    #pragma unroll
    for (int j = 0; j < 4; ++j) {
      int col = wc + j * 16 + lm;
      float bv = bias[bcol * 128 + col];
      #pragma unroll
      for (int p = 0; p < 4; ++p)
        Ts[(wr + i * 16 + q * 4 + p) * 136 + col] = __float2half(acc[i][j][p] + bv);
    }
  __syncthreads();
  int row = tid >> 1, half = tid & 1;
  size_t grow = (size_t)(brow * 128 + row);
  #pragma unroll
  for (int v = 0; v < 8; ++v) {
    int col = half * 64 + v * 8;
    UH t; t.v = *(const short8*)(Ts + row * 136 + col);
    UB o;
    #pragma unroll
    for (int e = 0; e < 8; ++e) o.e[e] = __float2bfloat16(fmaxf(__half2float(t.e[e]), 0.f));
    __builtin_nontemporal_store(o.v, (short8*)(out + grow * 512 + cout + bcol * 128 + col));
  }
}

// ---- GRU step GEMM: 64x64 tile (R13-green), NT loads for xpre ----
__global__ __launch_bounds__(256, 2)
void gruk(const bf16* __restrict__ A, const bf16* __restrict__ Bt,
          const bf16* __restrict__ xpre, int ldx, int mode,
          __half* __restrict__ zh, bf16* __restrict__ rhb,
          bf16* __restrict__ hsb)
{
  __shared__ __align__(16) char smem[16384];   // As 8K + Bs 8K; Ts (64x72 f16) alias
  bf16* As = (bf16*)smem;
  bf16* Bs = (bf16*)(smem + 8192);
  __half* Ts = (__half*)smem;

  const int tid  = threadIdx.x;
  const int wave = tid >> 6, lane = tid & 63;
  const int lm = lane & 15, q = lane >> 4;
  const int brow = blockIdx.x, bcol = blockIdx.y;
  const int srow = lane >> 3, sslot = lane & 7;

  f32x4 acc[4];
  #pragma unroll
  for (int j = 0; j < 4; ++j) acc[j] = (f32x4){0.f, 0.f, 0.f, 0.f};

  for (int kb = 0; kb < 512; kb += 64) {
    #pragma unroll
    for (int c = 0; c < 2; ++c) {
      int r = wave * 16 + c * 8 + srow;
      int cg = sslot ^ (r & 7);
      gl_lds16(A + (size_t)(brow * 64 + r) * 512 + kb + cg * 8,
               As + (wave * 16 + c * 8) * 64);
      gl_lds16(Bt + (size_t)(bcol * 64 + r) * 512 + kb + cg * 8,
               Bs + (wave * 16 + c * 8) * 64);
    }
    __syncthreads();
    #pragma unroll
    for (int ks = 0; ks < 2; ++ks) {
      int cg = ks * 4 + q;
      int ar = wave * 16 + lm;
      short8 af = *(const short8*)(As + ar * 64 + ((cg ^ (ar & 7)) * 8));
      #pragma unroll
      for (int j = 0; j < 4; ++j) {
        int nr = j * 16 + lm;
        short8 b8 = *(const short8*)(Bs + nr * 64 + ((cg ^ (nr & 7)) * 8));
        acc[j] = mfma16(af, b8, acc[j]);
      }
    }
    __syncthreads();
  }
  #pragma unroll
  for (int j = 0; j < 4; ++j)
    #pragma unroll
    for (int p = 0; p < 4; ++p)
      Ts[(wave * 16 + q * 4 + p) * 72 + j * 16 + lm] = __float2half(acc[j][p]);
  __syncthreads();
  int row = tid >> 2, quarter = tid & 3;
  size_t grow = (size_t)(brow * 64 + row);
  #pragma unroll
  for (int v = 0; v < 2; ++v) {
    int lcol = quarter * 16 + v * 8;
    int gcol = bcol * 64 + lcol;
    UH t; t.v = *(const short8*)(Ts + row * 72 + lcol);
    UB xv; xv.v = __builtin_nontemporal_load((const short8*)(xpre + grow * ldx + gcol));
    if (mode == 1) {
      if (bcol < 8) {                       // z gate
        UH o;
        #pragma unroll
        for (int e = 0; e < 8; ++e)
          o.e[e] = __float2half(sigf(__half2float(t.e[e]) + (float)xv.e[e]));
        *(short8*)(zh + grow * 512 + gcol) = o.v;
      } else {                              // r gate * h
        int rc = gcol - 512;
        UB h8; h8.v = *(const short8*)(hsb + grow * 512 + rc);
        UB o;
        #pragma unroll
        for (int e = 0; e < 8; ++e) {
          float s = sigf(__half2float(t.e[e]) + (float)xv.e[e]);
          o.e[e] = __float2bfloat16(s * (float)h8.e[e]);
        }
        *(short8*)(rhb + grow * 512 + rc) = o.v;
      }
    } else {                                // candidate + state update
      UB h8; h8.v = *(const short8*)(hsb + grow * 512 + gcol);
      UH z8; z8.v = *(const short8*)(zh + grow * 512 + gcol);
      UB o;
      #pragma unroll
      for (int e = 0; e < 8; ++e) {
        float c = tanhf(__half2float(t.e[e]) + (float)xv.e[e]);
        float zc = __half2float(z8.e[e]);
        o.e[e] = __float2bfloat16(zc * (float)h8.e[e] + (1.f - zc) * c);
      }
      *(short8*)(hsb + grow * 512 + gcol) = o.v;
    }
  }
}

// ---- one-shot weight transpose/convert ----
__global__ void prep(const float* __restrict__ Wh_zr, const float* __restrict__ Wh_c,
                     const float* __restrict__ Wx_zr, const float* __restrict__ Wx_c,
                     const float* __restrict__ W_gcn,
                     bf16* __restrict__ Whzrt, bf16* __restrict__ Whct,
                     bf16* __restrict__ Wxzrt, bf16* __restrict__ Wxct,
                     bf16* __restrict__ Wgt) {
  int i = blockIdx.x * 256 + threadIdx.x;   // grid 6272
  if (i < 524288) {
    int n = i >> 9, k = i & 511;
    Whzrt[i] = __float2bfloat16(Wh_zr[(size_t)k * 1024 + n]);
  } else if (i < 786432) {
    int j = i - 524288; int n = j >> 9, k = j & 511;
    Whct[j] = __float2bfloat16(Wh_c[(size_t)k * 512 + n]);
  } else if (i < 1310720) {
    int j = i - 786432; int n = j >> 9, k = j & 511;
    Wxzrt[j] = __float2bfloat16(Wx_zr[(size_t)k * 1024 + n]);
  } else if (i < 1572864) {
    int j = i - 1310720; int n = j >> 9, k = j & 511;
    Wxct[j] = __float2bfloat16(Wx_c[(size_t)k * 512 + n]);
  } else {
    int j = i - 1572864; int n = j >> 7, k = j & 127;
    Wgt[j] = __float2bfloat16(W_gcn[(size_t)k * 256 + n]);
  }
}

// ---- epilogue kernels (R13-green) ----
__global__ void norm_lvec(const bf16* __restrict__ hsb, const float* __restrict__ Wl,
                          const float* __restrict__ bl, const float* __restrict__ hv,
                          bf16* __restrict__ Htrb, float* __restrict__ lv,
                          float* __restrict__ hn) {
  int w = threadIdx.x >> 6, lane = threadIdx.x & 63;
  if (blockIdx.x == 1024) {
    float x[8], ss = 0.f;
    #pragma unroll
    for (int j = 0; j < 8; ++j) { x[j] = hv[w * 512 + lane * 8 + j]; ss += x[j] * x[j]; }
    ss = wred(ss);
    float inv = 1.f / fmaxf(sqrtf(ss), 1e-12f);
    #pragma unroll
    for (int j = 0; j < 8; ++j) hn[w * 512 + lane * 8 + j] = x[j] * inv;
    return;
  }
  int n = blockIdx.x * 4 + w;
  float x[8], ss = 0.f;
  #pragma unroll
  for (int j = 0; j < 8; ++j) {
    x[j] = (float)hsb[(size_t)n * 512 + lane * 8 + j];
    ss += x[j] * x[j];
  }
  ss = wred(ss);
  float inv = 1.f / fmaxf(sqrtf(ss), 1e-12f);
  float dot = 0.f;
  #pragma unroll
  for (int j = 0; j < 8; ++j) {
    float vv = x[j] * inv;
    Htrb[(size_t)n * 512 + lane * 8 + j] = __float2bfloat16(vv);
    dot += vv * Wl[lane * 8 + j];
  }
  dot = wred(dot);
  if (lane == 0) lv[n] = sigf(dot + bl[0]);
}

// htf with mkfinal folded in
__global__ void htf(const bf16* __restrict__ Htrb, const float* __restrict__ xf,
                    const float* __restrict__ Wc, const float* __restrict__ bc,
                    const float* __restrict__ lv, float* __restrict__ v) {
  __shared__ float fin_s[4][64];
  int ch = blockIdx.x;                              // grid 64, block 512
  int d = threadIdx.x;
  int n0 = ch * 64;
  if (d < 256) {
    int t = d >> 6, i = d & 63, n = n0 + i;
    float g = bc[t];
    #pragma unroll
    for (int tt = 0; tt < 5; ++tt) g += xf[tt * 4096 + n] * Wc[tt * 4 + t];
    fin_s[t][i] = lv[n] * g;
  }
  __syncthreads();
  float s0 = 0.f, s1 = 0.f, s2 = 0.f, s3 = 0.f;
  for (int i = 0; i < 64; ++i) {
    float hv = (float)Htrb[(size_t)(n0 + i) * 512 + d];
    s0 += hv * fin_s[0][i];
    s1 += hv * fin_s[1][i];
    s2 += hv * fin_s[2][i];
    s3 += hv * fin_s[3][i];
  }
  atomicAdd(&v[d], s0);
  atomicAdd(&v[512 + d], s1);
  atomicAdd(&v[1024 + d], s2);
  atomicAdd(&v[1536 + d], s3);
}

__global__ void attk(const bf16* __restrict__ Htrb, const float* __restrict__ v,
                     float* __restrict__ out) {
  int w = threadIdx.x >> 6, lane = threadIdx.x & 63;
  int n = blockIdx.x * 4 + w;
  float x[8];
  #pragma unroll
  for (int j = 0; j < 8; ++j) x[j] = (float)Htrb[(size_t)n * 512 + lane * 8 + j];
  #pragma unroll
  for (int t = 0; t < 4; ++t) {
    float s = 0.f;
    #pragma unroll
    for (int j = 0; j < 8; ++j) s += x[j] * v[t * 512 + lane * 8 + j];
    s = wred(s);
    if (lane == 0) out[t * 4096 + n] = s;
  }
}

__global__ void loff(const bf16* __restrict__ Htrb, const float* __restrict__ hn,
                     const int* __restrict__ ty, float* __restrict__ loffp) {
  int w = threadIdx.x >> 6, lane = threadIdx.x & 63;
  int t = blockIdx.y;
  int m = blockIdx.x * 4 + w;
  const int* row = ty + ((size_t)t * 2048 + m) * 18;
  int pi = row[1];
  float p[8], hv[8], c = 0.f;
  #pragma unroll
  for (int j = 0; j < 8; ++j) {
    p[j]  = (float)Htrb[(size_t)pi * 512 + lane * 8 + j];
    hv[j] = hn[t * 512 + lane * 8 + j];
    c += p[j] * hv[j];
  }
  c = wred(c);
  float a[8], sp = 0.f;
  #pragma unroll
  for (int j = 0; j < 8; ++j) { a[j] = p[j] - 2.f * c * hv[j]; sp += a[j] * p[j]; }
  sp = wred(sp);
  float acc = 0.f;
  for (int k = 0; k < 16; ++k) {
    int ni = row[2 + k];
    float sn = 0.f;
    #pragma unroll
    for (int j = 0; j < 8; ++j) sn += a[j] * (float)Htrb[(size_t)ni * 512 + lane * 8 + j];
    sn = wred(sn);
    acc += fmaxf(sn - sp + 0.5f, 0.f);
  }
  __shared__ float sbuf[4];
  if (lane == 0) sbuf[w] = acc;
  __syncthreads();
  if (threadIdx.x == 0)
    loffp[t * 512 + blockIdx.x] = sbuf[0] + sbuf[1] + sbuf[2] + sbuf[3];
}

__global__ void fini(const float* __restrict__ loffp, const float* __restrict__ lv,
                     const float* __restrict__ yl, float* __restrict__ out) {
  int tid = threadIdx.x, w = tid >> 6, lane = tid & 63;
  float s = 0.f, s2 = 0.f;
  for (int i = tid; i < 2048; i += 256) s += loffp[i];
  for (int i = tid; i < 4096; i += 256) {
    float l = lv[i];
    float ym = 0.25f * (yl[i] + yl[4096 + i] + yl[8192 + i] + yl[12288 + i]);
    s2 += fmaxf(l, 0.f) - l * ym + log1pf(expf(-fabsf(l)));
  }
  s = wred(s); s2 = wred(s2);
  __shared__ float sb[4], sb2[4];
  if (lane == 0) { sb[w] = s; sb2[w] = s2; }
  __syncthreads();
  if (tid == 0) {
    out[16384] = (sb[0] + sb[1] + sb[2] + sb[3]) / (4.f * 2048.f * 16.f);
    out[16385] = (sb2[0] + sb2[1] + sb2[2] + sb2[3]) / 4096.f;
  }
}

__global__ void wsprobe(float marker, float* out) {
  if (threadIdx.x == 0) out[0] = marker;
}

// ---------------- launch ----------------
extern "C" void kernel_launch(void* const* d_in, const int* in_sizes, int n_in,
                              void* d_out, int out_size, void* d_ws, size_t ws_size,
                              hipStream_t stream) {
  const float* x_feature   = (const float*)d_in[0];
  const float* x_graph     = (const float*)d_in[1];
  const float* x_graph_inv = (const float*)d_in[2];
  const int*   temp_y      = (const int*)d_in[3];
  const float* is_leaf     = (const float*)d_in[4];
  const float* W_gcn       = (const float*)d_in[5];
  const float* b_gcn       = (const float*)d_in[6];
  const float* Wx_zr       = (const float*)d_in[7];
  const float* Wh_zr       = (const float*)d_in[8];
  const float* b_zr        = (const float*)d_in[9];
  const float* Wx_c        = (const float*)d_in[10];
  const float* Wh_c        = (const float*)d_in[11];
  const float* b_c         = (const float*)d_in[12];
  const float* h_vecs      = (const float*)d_in[13];
  const float* W_leaf      = (const float*)d_in[14];
  const float* b_leaf      = (const float*)d_in[15];
  const float* W_conv      = (const float*)d_in[16];
  const float* b_conv      = (const float*)d_in[17];
  float* out = (float*)d_out;
  (void)in_sizes; (void)n_in; (void)out_size;

  const size_t NEED = 156000000;  // ~149 MB; ws_size = 268 MB (R7 fill evidence)
  if (ws_size < NEED) {
    wsprobe<<<1, 64, 0, stream>>>(1000.f + (float)(ws_size >> 20), out);
    return;
  }

  char* ws = (char*)d_ws;
  size_t off = 0;
  auto alloc = [&](size_t bytes) -> void* {
    void* p = ws + off;
    off = (off + bytes + 255) & ~(size_t)255;
    return p;
  };
  bf16*   Whzrt = (bf16*)  alloc((size_t)1024 * 512 * 2);
  bf16*   Whct  = (bf16*)  alloc((size_t)512 * 512 * 2);
  bf16*   Wxzrt = (bf16*)  alloc((size_t)1024 * 512 * 2);
  bf16*   Wxct  = (bf16*)  alloc((size_t)512 * 512 * 2);
  bf16*   Wgt   = (bf16*)  alloc((size_t)256 * 128 * 2);
  bf16*   hfin  = (bf16*)  alloc((size_t)32768 * 512 * 2);  // 32 MB
  bf16*   xzrp  = (bf16*)  alloc((size_t)32768 * 1024 * 2); // 64 MB (bias folded)
  bf16*   xcp   = (bf16*)  alloc((size_t)32768 * 512 * 2);  // 32 MB (bias folded)
  bf16*   hsb   = (bf16*)  alloc((size_t)4096 * 512 * 2);
  bf16*   rhb   = (bf16*)  alloc((size_t)4096 * 512 * 2);
  __half* zh    = (__half*)alloc((size_t)4096 * 512 * 2);
  float*  lv    = (float*) alloc(4096 * 4);
  float*  hn    = (float*) alloc(4 * 512 * 4);
  float*  v     = (float*) alloc(4 * 512 * 4);
  float*  loffp = (float*) alloc(2048 * 4);
  bf16*   Htrb  = hfin;   // overlay: hfin dead after gemmx consumes it

  hipMemsetAsync(hsb, 0, (size_t)4096 * 512 * 2, stream);   // h0 = 0
  hipMemsetAsync(v, 0, 4 * 512 * 4, stream);

  prep<<<6272, 256, 0, stream>>>(Wh_zr, Wh_c, Wx_zr, Wx_c, W_gcn,
                                 Whzrt, Whct, Wxzrt, Wxct, Wgt);
  gcnk<<<dim3(256, 2, 2), 256, 0, stream>>>(x_graph, x_graph_inv, Wgt, b_gcn, hfin);
  gemmx<<<dim3(256, 12), 256, 0, stream>>>(hfin, Wxzrt, Wxct, b_zr, b_c, xzrp, xcp);

  // sequential GRU: 64x64 tiles, 1024/512 blocks per launch
  for (int t = 0; t < 8; ++t) {
    const bf16* xz = xzrp + (size_t)t * 4096 * 1024;
    const bf16* xc = xcp + (size_t)t * 4096 * 512;
    gruk<<<dim3(64, 16), 256, 0, stream>>>(hsb, Whzrt, xz, 1024, 1, zh, rhb, hsb);
    gruk<<<dim3(64, 8), 256, 0, stream>>>(rhb, Whct, xc, 512, 2, zh, nullptr, hsb);
  }

  norm_lvec<<<1025, 256, 0, stream>>>(hsb, W_leaf, b_leaf, h_vecs, Htrb, lv, hn);
  htf<<<64, 512, 0, stream>>>(Htrb, x_feature, W_conv, b_conv, lv, v);
  attk<<<1024, 256, 0, stream>>>(Htrb, v, out);
  loff<<<dim3(512, 4), 256, 0, stream>>>(Htrb, hn, temp_y, loffp);
  fini<<<1, 256, 0, stream>>>(loffp, lv, is_leaf, out);
}

// Round 15
// 453.610 us; speedup vs baseline: 1.4961x; 1.4961x over previous
//
#include <hip/hip_runtime.h>
#include <hip/hip_bf16.h>
#include <hip/hip_fp16.h>
#include <math.h>

typedef __hip_bfloat16 bf16;
typedef __attribute__((ext_vector_type(8))) short short8;   // 8 bf16 / 8 f16 (16 B)
typedef __attribute__((ext_vector_type(4))) float f32x4;    // MFMA C/D frag

union UB { short8 v; bf16 e[8]; };
union UH { short8 v; __half e[8]; };

// ---------------- helpers ----------------
__device__ __forceinline__ float wred(float v) {
  #pragma unroll
  for (int o = 32; o > 0; o >>= 1) v += __shfl_xor(v, o, 64);
  return v;
}
__device__ __forceinline__ float sigf(float x) { return 1.f / (1.f + expf(-x)); }

__device__ __forceinline__ void gl_lds16(const bf16* g, const bf16* lds) {
  __builtin_amdgcn_global_load_lds((const __attribute__((address_space(1))) void*)g,
                                   (__attribute__((address_space(3))) void*)lds,
                                   16, 0, 0);
}
__device__ __forceinline__ f32x4 mfma16(short8 a, short8 b, f32x4 c) {
  return __builtin_amdgcn_mfma_f32_16x16x32_bf16(a, b, c, 0, 0, 0);
}

// ---- merged batch GEMM (R13-green, NT reverted): xzrp + xcp, K=512 ----
__global__ __launch_bounds__(256, 2)
void gemmx(const bf16* __restrict__ A, const bf16* __restrict__ Wxzrt,
           const bf16* __restrict__ Wxct, const float* __restrict__ b_zr,
           const float* __restrict__ b_c, bf16* __restrict__ xzrp,
           bf16* __restrict__ xcp)
{
  __shared__ __align__(16) char smem[34816];
  bf16* As = (bf16*)smem;
  bf16* Bs = (bf16*)(smem + 16384);
  __half* Ts = (__half*)smem;

  const int tid  = threadIdx.x;
  const int wave = tid >> 6, lane = tid & 63;
  const int lm = lane & 15, q = lane >> 4;
  const int brow = blockIdx.x, bcol = blockIdx.y;   // XCD-local brow
  const int wr = (wave >> 1) * 64, wc = (wave & 1) * 64;
  const int srow = lane >> 3, sslot = lane & 7;

  const bf16* Bt; const float* bias; bf16* C; int ldc, colbase;
  if (bcol < 8) { Bt = Wxzrt + (size_t)bcol * 128 * 512; bias = b_zr; C = xzrp; ldc = 1024; colbase = bcol * 128; }
  else          { Bt = Wxct + (size_t)(bcol - 8) * 128 * 512; bias = b_c; C = xcp; ldc = 512; colbase = (bcol - 8) * 128; }

  f32x4 acc[4][4];
  #pragma unroll
  for (int i = 0; i < 4; ++i)
    #pragma unroll
    for (int j = 0; j < 4; ++j) acc[i][j] = (f32x4){0.f, 0.f, 0.f, 0.f};

  for (int kb = 0; kb < 512; kb += 64) {
    #pragma unroll
    for (int j = 0; j < 4; ++j) {
      int ml = wave * 32 + j * 8 + srow;
      int cg = sslot ^ (ml & 7);
      gl_lds16(A + (size_t)(brow * 128 + ml) * 512 + kb + cg * 8, As + (wave * 4 + j) * 512);
      gl_lds16(Bt + (size_t)ml * 512 + kb + cg * 8, Bs + (wave * 4 + j) * 512);
    }
    __syncthreads();
    #pragma unroll
    for (int ks = 0; ks < 2; ++ks) {
      short8 af[4], bfr[4];
      #pragma unroll
      for (int i = 0; i < 4; ++i) {
        int cg = ks * 4 + q;
        int ml = wr + i * 16 + lm;
        af[i]  = *(const short8*)(As + ml * 64 + ((cg ^ (ml & 7)) * 8));
        int nl = wc + i * 16 + lm;
        bfr[i] = *(const short8*)(Bs + nl * 64 + ((cg ^ (nl & 7)) * 8));
      }
      #pragma unroll
      for (int i = 0; i < 4; ++i)
        #pragma unroll
        for (int j = 0; j < 4; ++j)
          acc[i][j] = mfma16(af[i], bfr[j], acc[i][j]);
    }
    __syncthreads();
  }
  #pragma unroll
  for (int i = 0; i < 4; ++i)
    #pragma unroll
    for (int j = 0; j < 4; ++j) {
      int col = wc + j * 16 + lm;
      float bv = bias[colbase + col];
      #pragma unroll
      for (int p = 0; p < 4; ++p)
        Ts[(wr + i * 16 + q * 4 + p) * 136 + col] = __float2half(acc[i][j][p] + bv);
    }
  __syncthreads();
  int row = tid >> 1, half = tid & 1;
  size_t grow = (size_t)(brow * 128 + row);
  #pragma unroll
  for (int v = 0; v < 8; ++v) {
    int col = half * 64 + v * 8;
    UH t; t.v = *(const short8*)(Ts + row * 136 + col);
    UB o;
    #pragma unroll
    for (int e = 0; e < 8; ++e) o.e[e] = __float2bfloat16(__half2float(t.e[e]));
    *(short8*)(C + grow * ldc + colbase + col) = o.v;
  }
}

// ---- GCN batch GEMM (R13-green): grid (256, 2, 2), brow fastest ----
__global__ __launch_bounds__(256, 2)
void gcnk(const float* __restrict__ Ag, const float* __restrict__ Agi,
          const bf16* __restrict__ Wgt, const float* __restrict__ bias,
          bf16* __restrict__ out)
{
  __shared__ __align__(16) char smem[34816];
  bf16* As = (bf16*)smem;
  bf16* Bs = (bf16*)(smem + 16384);
  __half* Ts = (__half*)smem;

  const int tid  = threadIdx.x;
  const int wave = tid >> 6, lane = tid & 63;
  const int lm = lane & 15, q = lane >> 4;
  const int brow = blockIdx.x, bcol = blockIdx.y;
  const int z = blockIdx.z, cout = z * 256;
  const float* A = z ? Agi : Ag;
  const int wr = (wave >> 1) * 64, wc = (wave & 1) * 64;
  const int srow = lane >> 3, sslot = lane & 7;

  f32x4 acc[4][4];
  #pragma unroll
  for (int i = 0; i < 4; ++i)
    #pragma unroll
    for (int j = 0; j < 4; ++j) acc[i][j] = (f32x4){0.f, 0.f, 0.f, 0.f};

  for (int kb = 0; kb < 128; kb += 64) {
    #pragma unroll
    for (int j = 0; j < 4; ++j) {
      int ml = wave * 32 + j * 8 + srow;
      int cg = sslot ^ (ml & 7);
      const float* src = A + (size_t)(brow * 128 + ml) * 128 + kb + cg * 8;
      bf16 tmp[8];
      #pragma unroll
      for (int e = 0; e < 8; ++e) tmp[e] = __float2bfloat16(src[e]);
      *(short8*)(As + ml * 64 + sslot * 8) = *(const short8*)tmp;
      gl_lds16(Wgt + (size_t)(bcol * 128 + ml) * 128 + kb + cg * 8,   // no cout!
               Bs + (wave * 4 + j) * 512);
    }
    __syncthreads();
    #pragma unroll
    for (int ks = 0; ks < 2; ++ks) {
      short8 af[4], bfr[4];
      #pragma unroll
      for (int i = 0; i < 4; ++i) {
        int cg = ks * 4 + q;
        int ml = wr + i * 16 + lm;
        af[i]  = *(const short8*)(As + ml * 64 + ((cg ^ (ml & 7)) * 8));
        int nl = wc + i * 16 + lm;
        bfr[i] = *(const short8*)(Bs + nl * 64 + ((cg ^ (nl & 7)) * 8));
      }
      #pragma unroll
      for (int i = 0; i < 4; ++i)
        #pragma unroll
        for (int j = 0; j < 4; ++j)
          acc[i][j] = mfma16(af[i], bfr[j], acc[i][j]);
    }
    __syncthreads();
  }
  #pragma unroll
  for (int i = 0; i < 4; ++i)
    #pragma unroll
    for (int j = 0; j < 4; ++j) {
      int col = wc + j * 16 + lm;
      float bv = bias[bcol * 128 + col];
      #pragma unroll
      for (int p = 0; p < 4; ++p)
        Ts[(wr + i * 16 + q * 4 + p) * 136 + col] = __float2half(acc[i][j][p] + bv);
    }
  __syncthreads();
  int row = tid >> 1, half = tid & 1;
  size_t grow = (size_t)(brow * 128 + row);
  #pragma unroll
  for (int v = 0; v < 8; ++v) {
    int col = half * 64 + v * 8;
    UH t; t.v = *(const short8*)(Ts + row * 136 + col);
    UB o;
    #pragma unroll
    for (int e = 0; e < 8; ++e) o.e[e] = __float2bfloat16(fmaxf(__half2float(t.e[e]), 0.f));
    *(short8*)(out + grow * 512 + cout + bcol * 128 + col) = o.v;
  }
}

// ---- GRU step GEMM: 64x64 tile, BK=128 (16 MFMA per barrier pair) ----------
// grid (64, 16) zr / (64, 8) c, brow fastest. LDS invariant: row r slot s
// (of 16) holds k-chunk s^(r&15). K-chunk order kb*128+ks*32 is monotone ==
// R13's kb*64+ks*32 order => bit-identical accumulation.
__global__ __launch_bounds__(256, 2)
void gruk(const bf16* __restrict__ A, const bf16* __restrict__ Bt,
          const bf16* __restrict__ xpre, int ldx, int mode,
          __half* __restrict__ zh, bf16* __restrict__ rhb,
          bf16* __restrict__ hsb)
{
  __shared__ __align__(16) char smem[32768];   // As 16K + Bs 16K; Ts (64x72 f16) alias
  bf16* As = (bf16*)smem;
  bf16* Bs = (bf16*)(smem + 16384);
  __half* Ts = (__half*)smem;

  const int tid  = threadIdx.x;
  const int wave = tid >> 6, lane = tid & 63;
  const int lm = lane & 15, q = lane >> 4;
  const int brow = blockIdx.x, bcol = blockIdx.y;
  const int srow4 = lane >> 4, sslot = lane & 15;   // 4 rows/call, 16 chunks/row

  f32x4 acc[4];
  #pragma unroll
  for (int j = 0; j < 4; ++j) acc[j] = (f32x4){0.f, 0.f, 0.f, 0.f};

  for (int kb = 0; kb < 512; kb += 128) {
    // stage A and B tiles (64 rows x 128 cols each): 4 calls/wave each,
    // 4 rows per call; lane's source chunk = sslot ^ (r & 15)
    #pragma unroll
    for (int c = 0; c < 4; ++c) {
      int r = wave * 16 + c * 4 + srow4;
      int cg = sslot ^ (r & 15);
      gl_lds16(A + (size_t)(brow * 64 + r) * 512 + kb + cg * 8,
               As + (wave * 16 + c * 4) * 128);
      gl_lds16(Bt + (size_t)(bcol * 64 + r) * 512 + kb + cg * 8,
               Bs + (wave * 16 + c * 4) * 128);
    }
    __syncthreads();
    #pragma unroll
    for (int ks = 0; ks < 4; ++ks) {
      int cg = ks * 4 + q;
      int ar = wave * 16 + lm;
      short8 af = *(const short8*)(As + ar * 128 + ((cg ^ (ar & 15)) * 8));
      #pragma unroll
      for (int j = 0; j < 4; ++j) {
        int nr = j * 16 + lm;
        short8 b8 = *(const short8*)(Bs + nr * 128 + ((cg ^ (nr & 15)) * 8));
        acc[j] = mfma16(af, b8, acc[j]);
      }
    }
    __syncthreads();
  }
  #pragma unroll
  for (int j = 0; j < 4; ++j)
    #pragma unroll
    for (int p = 0; p < 4; ++p)
      Ts[(wave * 16 + q * 4 + p) * 72 + j * 16 + lm] = __float2half(acc[j][p]);
  __syncthreads();
  int row = tid >> 2, quarter = tid & 3;
  size_t grow = (size_t)(brow * 64 + row);
  #pragma unroll
  for (int v = 0; v < 2; ++v) {
    int lcol = quarter * 16 + v * 8;
    int gcol = bcol * 64 + lcol;
    UH t; t.v = *(const short8*)(Ts + row * 72 + lcol);
    UB xv; xv.v = *(const short8*)(xpre + grow * ldx + gcol);
    if (mode == 1) {
      if (bcol < 8) {                       // z gate
        UH o;
        #pragma unroll
        for (int e = 0; e < 8; ++e)
          o.e[e] = __float2half(sigf(__half2float(t.e[e]) + (float)xv.e[e]));
        *(short8*)(zh + grow * 512 + gcol) = o.v;
      } else {                              // r gate * h
        int rc = gcol - 512;
        UB h8; h8.v = *(const short8*)(hsb + grow * 512 + rc);
        UB o;
        #pragma unroll
        for (int e = 0; e < 8; ++e) {
          float s = sigf(__half2float(t.e[e]) + (float)xv.e[e]);
          o.e[e] = __float2bfloat16(s * (float)h8.e[e]);
        }
        *(short8*)(rhb + grow * 512 + rc) = o.v;
      }
    } else {                                // candidate + state update
      UB h8; h8.v = *(const short8*)(hsb + grow * 512 + gcol);
      UH z8; z8.v = *(const short8*)(zh + grow * 512 + gcol);
      UB o;
      #pragma unroll
      for (int e = 0; e < 8; ++e) {
        float c = tanhf(__half2float(t.e[e]) + (float)xv.e[e]);
        float zc = __half2float(z8.e[e]);
        o.e[e] = __float2bfloat16(zc * (float)h8.e[e] + (1.f - zc) * c);
      }
      *(short8*)(hsb + grow * 512 + gcol) = o.v;
    }
  }
}

// ---- one-shot weight transpose/convert ----
__global__ void prep(const float* __restrict__ Wh_zr, const float* __restrict__ Wh_c,
                     const float* __restrict__ Wx_zr, const float* __restrict__ Wx_c,
                     const float* __restrict__ W_gcn,
                     bf16* __restrict__ Whzrt, bf16* __restrict__ Whct,
                     bf16* __restrict__ Wxzrt, bf16* __restrict__ Wxct,
                     bf16* __restrict__ Wgt) {
  int i = blockIdx.x * 256 + threadIdx.x;   // grid 6272
  if (i < 524288) {
    int n = i >> 9, k = i & 511;
    Whzrt[i] = __float2bfloat16(Wh_zr[(size_t)k * 1024 + n]);
  } else if (i < 786432) {
    int j = i - 524288; int n = j >> 9, k = j & 511;
    Whct[j] = __float2bfloat16(Wh_c[(size_t)k * 512 + n]);
  } else if (i < 1310720) {
    int j = i - 786432; int n = j >> 9, k = j & 511;
    Wxzrt[j] = __float2bfloat16(Wx_zr[(size_t)k * 1024 + n]);
  } else if (i < 1572864) {
    int j = i - 1310720; int n = j >> 9, k = j & 511;
    Wxct[j] = __float2bfloat16(Wx_c[(size_t)k * 512 + n]);
  } else {
    int j = i - 1572864; int n = j >> 7, k = j & 127;
    Wgt[j] = __float2bfloat16(W_gcn[(size_t)k * 256 + n]);
  }
}

// ---- epilogue kernels (R13-green) ----
__global__ void norm_lvec(const bf16* __restrict__ hsb, const float* __restrict__ Wl,
                          const float* __restrict__ bl, const float* __restrict__ hv,
                          bf16* __restrict__ Htrb, float* __restrict__ lv,
                          float* __restrict__ hn) {
  int w = threadIdx.x >> 6, lane = threadIdx.x & 63;
  if (blockIdx.x == 1024) {
    float x[8], ss = 0.f;
    #pragma unroll
    for (int j = 0; j < 8; ++j) { x[j] = hv[w * 512 + lane * 8 + j]; ss += x[j] * x[j]; }
    ss = wred(ss);
    float inv = 1.f / fmaxf(sqrtf(ss), 1e-12f);
    #pragma unroll
    for (int j = 0; j < 8; ++j) hn[w * 512 + lane * 8 + j] = x[j] * inv;
    return;
  }
  int n = blockIdx.x * 4 + w;
  float x[8], ss = 0.f;
  #pragma unroll
  for (int j = 0; j < 8; ++j) {
    x[j] = (float)hsb[(size_t)n * 512 + lane * 8 + j];
    ss += x[j] * x[j];
  }
  ss = wred(ss);
  float inv = 1.f / fmaxf(sqrtf(ss), 1e-12f);
  float dot = 0.f;
  #pragma unroll
  for (int j = 0; j < 8; ++j) {
    float vv = x[j] * inv;
    Htrb[(size_t)n * 512 + lane * 8 + j] = __float2bfloat16(vv);
    dot += vv * Wl[lane * 8 + j];
  }
  dot = wred(dot);
  if (lane == 0) lv[n] = sigf(dot + bl[0]);
}

// htf with mkfinal folded in
__global__ void htf(const bf16* __restrict__ Htrb, const float* __restrict__ xf,
                    const float* __restrict__ Wc, const float* __restrict__ bc,
                    const float* __restrict__ lv, float* __restrict__ v) {
  __shared__ float fin_s[4][64];
  int ch = blockIdx.x;                              // grid 64, block 512
  int d = threadIdx.x;
  int n0 = ch * 64;
  if (d < 256) {
    int t = d >> 6, i = d & 63, n = n0 + i;
    float g = bc[t];
    #pragma unroll
    for (int tt = 0; tt < 5; ++tt) g += xf[tt * 4096 + n] * Wc[tt * 4 + t];
    fin_s[t][i] = lv[n] * g;
  }
  __syncthreads();
  float s0 = 0.f, s1 = 0.f, s2 = 0.f, s3 = 0.f;
  for (int i = 0; i < 64; ++i) {
    float hv = (float)Htrb[(size_t)(n0 + i) * 512 + d];
    s0 += hv * fin_s[0][i];
    s1 += hv * fin_s[1][i];
    s2 += hv * fin_s[2][i];
    s3 += hv * fin_s[3][i];
  }
  atomicAdd(&v[d], s0);
  atomicAdd(&v[512 + d], s1);
  atomicAdd(&v[1024 + d], s2);
  atomicAdd(&v[1536 + d], s3);
}

__global__ void attk(const bf16* __restrict__ Htrb, const float* __restrict__ v,
                     float* __restrict__ out) {
  int w = threadIdx.x >> 6, lane = threadIdx.x & 63;
  int n = blockIdx.x * 4 + w;
  float x[8];
  #pragma unroll
  for (int j = 0; j < 8; ++j) x[j] = (float)Htrb[(size_t)n * 512 + lane * 8 + j];
  #pragma unroll
  for (int t = 0; t < 4; ++t) {
    float s = 0.f;
    #pragma unroll
    for (int j = 0; j < 8; ++j) s += x[j] * v[t * 512 + lane * 8 + j];
    s = wred(s);
    if (lane == 0) out[t * 4096 + n] = s;
  }
}

__global__ void loff(const bf16* __restrict__ Htrb, const float* __restrict__ hn,
                     const int* __restrict__ ty, float* __restrict__ loffp) {
  int w = threadIdx.x >> 6, lane = threadIdx.x & 63;
  int t = blockIdx.y;
  int m = blockIdx.x * 4 + w;
  const int* row = ty + ((size_t)t * 2048 + m) * 18;
  int pi = row[1];
  float p[8], hv[8], c = 0.f;
  #pragma unroll
  for (int j = 0; j < 8; ++j) {
    p[j]  = (float)Htrb[(size_t)pi * 512 + lane * 8 + j];
    hv[j] = hn[t * 512 + lane * 8 + j];
    c += p[j] * hv[j];
  }
  c = wred(c);
  float a[8], sp = 0.f;
  #pragma unroll
  for (int j = 0; j < 8; ++j) { a[j] = p[j] - 2.f * c * hv[j]; sp += a[j] * p[j]; }
  sp = wred(sp);
  float acc = 0.f;
  for (int k = 0; k < 16; ++k) {
    int ni = row[2 + k];
    float sn = 0.f;
    #pragma unroll
    for (int j = 0; j < 8; ++j) sn += a[j] * (float)Htrb[(size_t)ni * 512 + lane * 8 + j];
    sn = wred(sn);
    acc += fmaxf(sn - sp + 0.5f, 0.f);
  }
  __shared__ float sbuf[4];
  if (lane == 0) sbuf[w] = acc;
  __syncthreads();
  if (threadIdx.x == 0)
    loffp[t * 512 + blockIdx.x] = sbuf[0] + sbuf[1] + sbuf[2] + sbuf[3];
}

__global__ void fini(const float* __restrict__ loffp, const float* __restrict__ lv,
                     const float* __restrict__ yl, float* __restrict__ out) {
  int tid = threadIdx.x, w = tid >> 6, lane = tid & 63;
  float s = 0.f, s2 = 0.f;
  for (int i = tid; i < 2048; i += 256) s += loffp[i];
  for (int i = tid; i < 4096; i += 256) {
    float l = lv[i];
    float ym = 0.25f * (yl[i] + yl[4096 + i] + yl[8192 + i] + yl[12288 + i]);
    s2 += fmaxf(l, 0.f) - l * ym + log1pf(expf(-fabsf(l)));
  }
  s = wred(s); s2 = wred(s2);
  __shared__ float sb[4], sb2[4];
  if (lane == 0) { sb[w] = s; sb2[w] = s2; }
  __syncthreads();
  if (tid == 0) {
    out[16384] = (sb[0] + sb[1] + sb[2] + sb[3]) / (4.f * 2048.f * 16.f);
    out[16385] = (sb2[0] + sb2[1] + sb2[2] + sb2[3]) / 4096.f;
  }
}

__global__ void wsprobe(float marker, float* out) {
  if (threadIdx.x == 0) out[0] = marker;
}

// ---------------- launch ----------------
extern "C" void kernel_launch(void* const* d_in, const int* in_sizes, int n_in,
                              void* d_out, int out_size, void* d_ws, size_t ws_size,
                              hipStream_t stream) {
  const float* x_feature   = (const float*)d_in[0];
  const float* x_graph     = (const float*)d_in[1];
  const float* x_graph_inv = (const float*)d_in[2];
  const int*   temp_y      = (const int*)d_in[3];
  const float* is_leaf     = (const float*)d_in[4];
  const float* W_gcn       = (const float*)d_in[5];
  const float* b_gcn       = (const float*)d_in[6];
  const float* Wx_zr       = (const float*)d_in[7];
  const float* Wh_zr       = (const float*)d_in[8];
  const float* b_zr        = (const float*)d_in[9];
  const float* Wx_c        = (const float*)d_in[10];
  const float* Wh_c        = (const float*)d_in[11];
  const float* b_c         = (const float*)d_in[12];
  const float* h_vecs      = (const float*)d_in[13];
  const float* W_leaf      = (const float*)d_in[14];
  const float* b_leaf      = (const float*)d_in[15];
  const float* W_conv      = (const float*)d_in[16];
  const float* b_conv      = (const float*)d_in[17];
  float* out = (float*)d_out;
  (void)in_sizes; (void)n_in; (void)out_size;

  const size_t NEED = 156000000;  // ~149 MB; ws_size = 268 MB (R7 fill evidence)
  if (ws_size < NEED) {
    wsprobe<<<1, 64, 0, stream>>>(1000.f + (float)(ws_size >> 20), out);
    return;
  }

  char* ws = (char*)d_ws;
  size_t off = 0;
  auto alloc = [&](size_t bytes) -> void* {
    void* p = ws + off;
    off = (off + bytes + 255) & ~(size_t)255;
    return p;
  };
  bf16*   Whzrt = (bf16*)  alloc((size_t)1024 * 512 * 2);
  bf16*   Whct  = (bf16*)  alloc((size_t)512 * 512 * 2);
  bf16*   Wxzrt = (bf16*)  alloc((size_t)1024 * 512 * 2);
  bf16*   Wxct  = (bf16*)  alloc((size_t)512 * 512 * 2);
  bf16*   Wgt   = (bf16*)  alloc((size_t)256 * 128 * 2);
  bf16*   hfin  = (bf16*)  alloc((size_t)32768 * 512 * 2);  // 32 MB
  bf16*   xzrp  = (bf16*)  alloc((size_t)32768 * 1024 * 2); // 64 MB (bias folded)
  bf16*   xcp   = (bf16*)  alloc((size_t)32768 * 512 * 2);  // 32 MB (bias folded)
  bf16*   hsb   = (bf16*)  alloc((size_t)4096 * 512 * 2);
  bf16*   rhb   = (bf16*)  alloc((size_t)4096 * 512 * 2);
  __half* zh    = (__half*)alloc((size_t)4096 * 512 * 2);
  float*  lv    = (float*) alloc(4096 * 4);
  float*  hn    = (float*) alloc(4 * 512 * 4);
  float*  v     = (float*) alloc(4 * 512 * 4);
  float*  loffp = (float*) alloc(2048 * 4);
  bf16*   Htrb  = hfin;   // overlay: hfin dead after gemmx consumes it

  hipMemsetAsync(hsb, 0, (size_t)4096 * 512 * 2, stream);   // h0 = 0
  hipMemsetAsync(v, 0, 4 * 512 * 4, stream);

  prep<<<6272, 256, 0, stream>>>(Wh_zr, Wh_c, Wx_zr, Wx_c, W_gcn,
                                 Whzrt, Whct, Wxzrt, Wxct, Wgt);
  gcnk<<<dim3(256, 2, 2), 256, 0, stream>>>(x_graph, x_graph_inv, Wgt, b_gcn, hfin);
  gemmx<<<dim3(256, 12), 256, 0, stream>>>(hfin, Wxzrt, Wxct, b_zr, b_c, xzrp, xcp);

  // sequential GRU: 64x64 tiles, BK=128, 1024/512 blocks per launch
  for (int t = 0; t < 8; ++t) {
    const bf16* xz = xzrp + (size_t)t * 4096 * 1024;
    const bf16* xc = xcp + (size_t)t * 4096 * 512;
    gruk<<<dim3(64, 16), 256, 0, stream>>>(hsb, Whzrt, xz, 1024, 1, zh, rhb, hsb);
    gruk<<<dim3(64, 8), 256, 0, stream>>>(rhb, Whct, xc, 512, 2, zh, nullptr, hsb);
  }

  norm_lvec<<<1025, 256, 0, stream>>>(hsb, W_leaf, b_leaf, h_vecs, Htrb, lv, hn);
  htf<<<64, 512, 0, stream>>>(Htrb, x_feature, W_conv, b_conv, lv, v);
  attk<<<1024, 256, 0, stream>>>(Htrb, v, out);
  loff<<<dim3(512, 4), 256, 0, stream>>>(Htrb, hn, temp_y, loffp);
  fini<<<1, 256, 0, stream>>>(loffp, lv, is_leaf, out);
}

// Round 16
// 404.821 us; speedup vs baseline: 1.6764x; 1.1205x over previous
//
#include <hip/hip_runtime.h>
#include <hip/hip_bf16.h>
#include <hip/hip_fp16.h>
#include <math.h>

typedef __hip_bfloat16 bf16;
typedef __attribute__((ext_vector_type(8))) short short8;   // 8 bf16 / 8 f16 (16 B)
typedef __attribute__((ext_vector_type(4))) float f32x4;    // MFMA C/D frag

union UB { short8 v; bf16 e[8]; };
union UH { short8 v; __half e[8]; };

// ---------------- helpers ----------------
__device__ __forceinline__ float wred(float v) {
  #pragma unroll
  for (int o = 32; o > 0; o >>= 1) v += __shfl_xor(v, o, 64);
  return v;
}
__device__ __forceinline__ float sigf(float x) { return 1.f / (1.f + expf(-x)); }

__device__ __forceinline__ void gl_lds16(const bf16* g, const bf16* lds) {
  __builtin_amdgcn_global_load_lds((const __attribute__((address_space(1))) void*)g,
                                   (__attribute__((address_space(3))) void*)lds,
                                   16, 0, 0);
}
__device__ __forceinline__ f32x4 mfma16(short8 a, short8 b, f32x4 c) {
  return __builtin_amdgcn_mfma_f32_16x16x32_bf16(a, b, c, 0, 0, 0);
}

// ---- merged batch GEMM: xzrp + xcp, K=512, line-coalesced epilogue ----
__global__ __launch_bounds__(256, 2)
void gemmx(const bf16* __restrict__ A, const bf16* __restrict__ Wxzrt,
           const bf16* __restrict__ Wxct, const float* __restrict__ b_zr,
           const float* __restrict__ b_c, bf16* __restrict__ xzrp,
           bf16* __restrict__ xcp)
{
  __shared__ __align__(16) char smem[34816];
  bf16* As = (bf16*)smem;
  bf16* Bs = (bf16*)(smem + 16384);
  __half* Ts = (__half*)smem;

  const int tid  = threadIdx.x;
  const int wave = tid >> 6, lane = tid & 63;
  const int lm = lane & 15, q = lane >> 4;
  const int brow = blockIdx.x, bcol = blockIdx.y;   // XCD-local brow
  const int wr = (wave >> 1) * 64, wc = (wave & 1) * 64;
  const int srow = lane >> 3, sslot = lane & 7;

  const bf16* Bt; const float* bias; bf16* C; int ldc, colbase;
  if (bcol < 8) { Bt = Wxzrt + (size_t)bcol * 128 * 512; bias = b_zr; C = xzrp; ldc = 1024; colbase = bcol * 128; }
  else          { Bt = Wxct + (size_t)(bcol - 8) * 128 * 512; bias = b_c; C = xcp; ldc = 512; colbase = (bcol - 8) * 128; }

  f32x4 acc[4][4];
  #pragma unroll
  for (int i = 0; i < 4; ++i)
    #pragma unroll
    for (int j = 0; j < 4; ++j) acc[i][j] = (f32x4){0.f, 0.f, 0.f, 0.f};

  for (int kb = 0; kb < 512; kb += 64) {
    #pragma unroll
    for (int j = 0; j < 4; ++j) {
      int ml = wave * 32 + j * 8 + srow;
      int cg = sslot ^ (ml & 7);
      gl_lds16(A + (size_t)(brow * 128 + ml) * 512 + kb + cg * 8, As + (wave * 4 + j) * 512);
      gl_lds16(Bt + (size_t)ml * 512 + kb + cg * 8, Bs + (wave * 4 + j) * 512);
    }
    __syncthreads();
    #pragma unroll
    for (int ks = 0; ks < 2; ++ks) {
      short8 af[4], bfr[4];
      #pragma unroll
      for (int i = 0; i < 4; ++i) {
        int cg = ks * 4 + q;
        int ml = wr + i * 16 + lm;
        af[i]  = *(const short8*)(As + ml * 64 + ((cg ^ (ml & 7)) * 8));
        int nl = wc + i * 16 + lm;
        bfr[i] = *(const short8*)(Bs + nl * 64 + ((cg ^ (nl & 7)) * 8));
      }
      #pragma unroll
      for (int i = 0; i < 4; ++i)
        #pragma unroll
        for (int j = 0; j < 4; ++j)
          acc[i][j] = mfma16(af[i], bfr[j], acc[i][j]);
    }
    __syncthreads();
  }
  #pragma unroll
  for (int i = 0; i < 4; ++i)
    #pragma unroll
    for (int j = 0; j < 4; ++j) {
      int col = wc + j * 16 + lm;
      float bv = bias[colbase + col];
      #pragma unroll
      for (int p = 0; p < 4; ++p)
        Ts[(wr + i * 16 + q * 4 + p) * 136 + col] = __float2half(acc[i][j][p] + bv);
    }
  __syncthreads();
  // line-coalesced: 16 consecutive lanes cover one row's 128 cols (256 B)
  int rg = tid >> 4, cl = tid & 15;
  #pragma unroll
  for (int v = 0; v < 8; ++v) {
    int row = v * 16 + rg;
    UH t; t.v = *(const short8*)(Ts + row * 136 + cl * 8);
    UB o;
    #pragma unroll
    for (int e = 0; e < 8; ++e) o.e[e] = __float2bfloat16(__half2float(t.e[e]));
    *(short8*)(C + (size_t)(brow * 128 + row) * ldc + colbase + cl * 8) = o.v;
  }
}

// ---- GCN batch GEMM: grid (256, 2, 2), line-coalesced epilogue ----
__global__ __launch_bounds__(256, 2)
void gcnk(const float* __restrict__ Ag, const float* __restrict__ Agi,
          const bf16* __restrict__ Wgt, const float* __restrict__ bias,
          bf16* __restrict__ out)
{
  __shared__ __align__(16) char smem[34816];
  bf16* As = (bf16*)smem;
  bf16* Bs = (bf16*)(smem + 16384);
  __half* Ts = (__half*)smem;

  const int tid  = threadIdx.x;
  const int wave = tid >> 6, lane = tid & 63;
  const int lm = lane & 15, q = lane >> 4;
  const int brow = blockIdx.x, bcol = blockIdx.y;
  const int z = blockIdx.z, cout = z * 256;
  const float* A = z ? Agi : Ag;
  const int wr = (wave >> 1) * 64, wc = (wave & 1) * 64;
  const int srow = lane >> 3, sslot = lane & 7;

  f32x4 acc[4][4];
  #pragma unroll
  for (int i = 0; i < 4; ++i)
    #pragma unroll
    for (int j = 0; j < 4; ++j) acc[i][j] = (f32x4){0.f, 0.f, 0.f, 0.f};

  for (int kb = 0; kb < 128; kb += 64) {
    #pragma unroll
    for (int j = 0; j < 4; ++j) {
      int ml = wave * 32 + j * 8 + srow;
      int cg = sslot ^ (ml & 7);
      const float* src = A + (size_t)(brow * 128 + ml) * 128 + kb + cg * 8;
      bf16 tmp[8];
      #pragma unroll
      for (int e = 0; e < 8; ++e) tmp[e] = __float2bfloat16(src[e]);
      *(short8*)(As + ml * 64 + sslot * 8) = *(const short8*)tmp;
      gl_lds16(Wgt + (size_t)(bcol * 128 + ml) * 128 + kb + cg * 8,   // no cout!
               Bs + (wave * 4 + j) * 512);
    }
    __syncthreads();
    #pragma unroll
    for (int ks = 0; ks < 2; ++ks) {
      short8 af[4], bfr[4];
      #pragma unroll
      for (int i = 0; i < 4; ++i) {
        int cg = ks * 4 + q;
        int ml = wr + i * 16 + lm;
        af[i]  = *(const short8*)(As + ml * 64 + ((cg ^ (ml & 7)) * 8));
        int nl = wc + i * 16 + lm;
        bfr[i] = *(const short8*)(Bs + nl * 64 + ((cg ^ (nl & 7)) * 8));
      }
      #pragma unroll
      for (int i = 0; i < 4; ++i)
        #pragma unroll
        for (int j = 0; j < 4; ++j)
          acc[i][j] = mfma16(af[i], bfr[j], acc[i][j]);
    }
    __syncthreads();
  }
  #pragma unroll
  for (int i = 0; i < 4; ++i)
    #pragma unroll
    for (int j = 0; j < 4; ++j) {
      int col = wc + j * 16 + lm;
      float bv = bias[bcol * 128 + col];
      #pragma unroll
      for (int p = 0; p < 4; ++p)
        Ts[(wr + i * 16 + q * 4 + p) * 136 + col] = __float2half(acc[i][j][p] + bv);
    }
  __syncthreads();
  int rg = tid >> 4, cl = tid & 15;
  #pragma unroll
  for (int v = 0; v < 8; ++v) {
    int row = v * 16 + rg;
    UH t; t.v = *(const short8*)(Ts + row * 136 + cl * 8);
    UB o;
    #pragma unroll
    for (int e = 0; e < 8; ++e) o.e[e] = __float2bfloat16(fmaxf(__half2float(t.e[e]), 0.f));
    *(short8*)(out + (size_t)(brow * 128 + row) * 512 + cout + bcol * 128 + cl * 8) = o.v;
  }
}

// ---- GRU step GEMM: 64x64 tile, BK=128, line-coalesced epilogue ------------
__global__ __launch_bounds__(256, 2)
void gruk(const bf16* __restrict__ A, const bf16* __restrict__ Bt,
          const bf16* __restrict__ xpre, int ldx, int mode,
          __half* __restrict__ zh, bf16* __restrict__ rhb,
          bf16* __restrict__ hsb)
{
  __shared__ __align__(16) char smem[32768];   // As 16K + Bs 16K; Ts (64x72 f16) alias
  bf16* As = (bf16*)smem;
  bf16* Bs = (bf16*)(smem + 16384);
  __half* Ts = (__half*)smem;

  const int tid  = threadIdx.x;
  const int wave = tid >> 6, lane = tid & 63;
  const int lm = lane & 15, q = lane >> 4;
  const int brow = blockIdx.x, bcol = blockIdx.y;
  const int srow4 = lane >> 4, sslot = lane & 15;

  f32x4 acc[4];
  #pragma unroll
  for (int j = 0; j < 4; ++j) acc[j] = (f32x4){0.f, 0.f, 0.f, 0.f};

  for (int kb = 0; kb < 512; kb += 128) {
    #pragma unroll
    for (int c = 0; c < 4; ++c) {
      int r = wave * 16 + c * 4 + srow4;
      int cg = sslot ^ (r & 15);
      gl_lds16(A + (size_t)(brow * 64 + r) * 512 + kb + cg * 8,
               As + (wave * 16 + c * 4) * 128);
      gl_lds16(Bt + (size_t)(bcol * 64 + r) * 512 + kb + cg * 8,
               Bs + (wave * 16 + c * 4) * 128);
    }
    __syncthreads();
    #pragma unroll
    for (int ks = 0; ks < 4; ++ks) {
      int cg = ks * 4 + q;
      int ar = wave * 16 + lm;
      short8 af = *(const short8*)(As + ar * 128 + ((cg ^ (ar & 15)) * 8));
      #pragma unroll
      for (int j = 0; j < 4; ++j) {
        int nr = j * 16 + lm;
        short8 b8 = *(const short8*)(Bs + nr * 128 + ((cg ^ (nr & 15)) * 8));
        acc[j] = mfma16(af, b8, acc[j]);
      }
    }
    __syncthreads();
  }
  #pragma unroll
  for (int j = 0; j < 4; ++j)
    #pragma unroll
    for (int p = 0; p < 4; ++p)
      Ts[(wave * 16 + q * 4 + p) * 72 + j * 16 + lm] = __float2half(acc[j][p]);
  __syncthreads();
  // line-coalesced: 8 consecutive lanes cover one row's 64 cols (128 B line)
  int rg = tid >> 3, cl = tid & 7;
  #pragma unroll
  for (int v = 0; v < 2; ++v) {
    int row = v * 32 + rg;
    int lcol = cl * 8;
    int gcol = bcol * 64 + lcol;
    size_t grow = (size_t)(brow * 64 + row);
    UH t; t.v = *(const short8*)(Ts + row * 72 + lcol);
    UB xv; xv.v = *(const short8*)(xpre + grow * ldx + gcol);
    if (mode == 1) {
      if (bcol < 8) {                       // z gate
        UH o;
        #pragma unroll
        for (int e = 0; e < 8; ++e)
          o.e[e] = __float2half(sigf(__half2float(t.e[e]) + (float)xv.e[e]));
        *(short8*)(zh + grow * 512 + gcol) = o.v;
      } else {                              // r gate * h
        int rc = gcol - 512;
        UB h8; h8.v = *(const short8*)(hsb + grow * 512 + rc);
        UB o;
        #pragma unroll
        for (int e = 0; e < 8; ++e) {
          float s = sigf(__half2float(t.e[e]) + (float)xv.e[e]);
          o.e[e] = __float2bfloat16(s * (float)h8.e[e]);
        }
        *(short8*)(rhb + grow * 512 + rc) = o.v;
      }
    } else {                                // candidate + state update
      UB h8; h8.v = *(const short8*)(hsb + grow * 512 + gcol);
      UH z8; z8.v = *(const short8*)(zh + grow * 512 + gcol);
      UB o;
      #pragma unroll
      for (int e = 0; e < 8; ++e) {
        float c = tanhf(__half2float(t.e[e]) + (float)xv.e[e]);
        float zc = __half2float(z8.e[e]);
        o.e[e] = __float2bfloat16(zc * (float)h8.e[e] + (1.f - zc) * c);
      }
      *(short8*)(hsb + grow * 512 + gcol) = o.v;
    }
  }
}

// ---- one-shot weight transpose/convert ----
__global__ void prep(const float* __restrict__ Wh_zr, const float* __restrict__ Wh_c,
                     const float* __restrict__ Wx_zr, const float* __restrict__ Wx_c,
                     const float* __restrict__ W_gcn,
                     bf16* __restrict__ Whzrt, bf16* __restrict__ Whct,
                     bf16* __restrict__ Wxzrt, bf16* __restrict__ Wxct,
                     bf16* __restrict__ Wgt) {
  int i = blockIdx.x * 256 + threadIdx.x;   // grid 6272
  if (i < 524288) {
    int n = i >> 9, k = i & 511;
    Whzrt[i] = __float2bfloat16(Wh_zr[(size_t)k * 1024 + n]);
  } else if (i < 786432) {
    int j = i - 524288; int n = j >> 9, k = j & 511;
    Whct[j] = __float2bfloat16(Wh_c[(size_t)k * 512 + n]);
  } else if (i < 1310720) {
    int j = i - 786432; int n = j >> 9, k = j & 511;
    Wxzrt[j] = __float2bfloat16(Wx_zr[(size_t)k * 1024 + n]);
  } else if (i < 1572864) {
    int j = i - 1310720; int n = j >> 9, k = j & 511;
    Wxct[j] = __float2bfloat16(Wx_c[(size_t)k * 512 + n]);
  } else {
    int j = i - 1572864; int n = j >> 7, k = j & 127;
    Wgt[j] = __float2bfloat16(W_gcn[(size_t)k * 256 + n]);
  }
}

// ---- epilogue kernels (green since R13) ----
__global__ void norm_lvec(const bf16* __restrict__ hsb, const float* __restrict__ Wl,
                          const float* __restrict__ bl, const float* __restrict__ hv,
                          bf16* __restrict__ Htrb, float* __restrict__ lv,
                          float* __restrict__ hn) {
  int w = threadIdx.x >> 6, lane = threadIdx.x & 63;
  if (blockIdx.x == 1024) {
    float x[8], ss = 0.f;
    #pragma unroll
    for (int j = 0; j < 8; ++j) { x[j] = hv[w * 512 + lane * 8 + j]; ss += x[j] * x[j]; }
    ss = wred(ss);
    float inv = 1.f / fmaxf(sqrtf(ss), 1e-12f);
    #pragma unroll
    for (int j = 0; j < 8; ++j) hn[w * 512 + lane * 8 + j] = x[j] * inv;
    return;
  }
  int n = blockIdx.x * 4 + w;
  float x[8], ss = 0.f;
  #pragma unroll
  for (int j = 0; j < 8; ++j) {
    x[j] = (float)hsb[(size_t)n * 512 + lane * 8 + j];
    ss += x[j] * x[j];
  }
  ss = wred(ss);
  float inv = 1.f / fmaxf(sqrtf(ss), 1e-12f);
  float dot = 0.f;
  #pragma unroll
  for (int j = 0; j < 8; ++j) {
    float vv = x[j] * inv;
    Htrb[(size_t)n * 512 + lane * 8 + j] = __float2bfloat16(vv);
    dot += vv * Wl[lane * 8 + j];
  }
  dot = wred(dot);
  if (lane == 0) lv[n] = sigf(dot + bl[0]);
}

// htf with mkfinal folded in
__global__ void htf(const bf16* __restrict__ Htrb, const float* __restrict__ xf,
                    const float* __restrict__ Wc, const float* __restrict__ bc,
                    const float* __restrict__ lv, float* __restrict__ v) {
  __shared__ float fin_s[4][64];
  int ch = blockIdx.x;                              // grid 64, block 512
  int d = threadIdx.x;
  int n0 = ch * 64;
  if (d < 256) {
    int t = d >> 6, i = d & 63, n = n0 + i;
    float g = bc[t];
    #pragma unroll
    for (int tt = 0; tt < 5; ++tt) g += xf[tt * 4096 + n] * Wc[tt * 4 + t];
    fin_s[t][i] = lv[n] * g;
  }
  __syncthreads();
  float s0 = 0.f, s1 = 0.f, s2 = 0.f, s3 = 0.f;
  for (int i = 0; i < 64; ++i) {
    float hv = (float)Htrb[(size_t)(n0 + i) * 512 + d];
    s0 += hv * fin_s[0][i];
    s1 += hv * fin_s[1][i];
    s2 += hv * fin_s[2][i];
    s3 += hv * fin_s[3][i];
  }
  atomicAdd(&v[d], s0);
  atomicAdd(&v[512 + d], s1);
  atomicAdd(&v[1024 + d], s2);
  atomicAdd(&v[1536 + d], s3);
}

__global__ void attk(const bf16* __restrict__ Htrb, const float* __restrict__ v,
                     float* __restrict__ out) {
  int w = threadIdx.x >> 6, lane = threadIdx.x & 63;
  int n = blockIdx.x * 4 + w;
  float x[8];
  #pragma unroll
  for (int j = 0; j < 8; ++j) x[j] = (float)Htrb[(size_t)n * 512 + lane * 8 + j];
  #pragma unroll
  for (int t = 0; t < 4; ++t) {
    float s = 0.f;
    #pragma unroll
    for (int j = 0; j < 8; ++j) s += x[j] * v[t * 512 + lane * 8 + j];
    s = wred(s);
    if (lane == 0) out[t * 4096 + n] = s;
  }
}

__global__ void loff(const bf16* __restrict__ Htrb, const float* __restrict__ hn,
                     const int* __restrict__ ty, float* __restrict__ loffp) {
  int w = threadIdx.x >> 6, lane = threadIdx.x & 63;
  int t = blockIdx.y;
  int m = blockIdx.x * 4 + w;
  const int* row = ty + ((size_t)t * 2048 + m) * 18;
  int pi = row[1];
  float p[8], hv[8], c = 0.f;
  #pragma unroll
  for (int j = 0; j < 8; ++j) {
    p[j]  = (float)Htrb[(size_t)pi * 512 + lane * 8 + j];
    hv[j] = hn[t * 512 + lane * 8 + j];
    c += p[j] * hv[j];
  }
  c = wred(c);
  float a[8], sp = 0.f;
  #pragma unroll
  for (int j = 0; j < 8; ++j) { a[j] = p[j] - 2.f * c * hv[j]; sp += a[j] * p[j]; }
  sp = wred(sp);
  float acc = 0.f;
  for (int k = 0; k < 16; ++k) {
    int ni = row[2 + k];
    float sn = 0.f;
    #pragma unroll
    for (int j = 0; j < 8; ++j) sn += a[j] * (float)Htrb[(size_t)ni * 512 + lane * 8 + j];
    sn = wred(sn);
    acc += fmaxf(sn - sp + 0.5f, 0.f);
  }
  __shared__ float sbuf[4];
  if (lane == 0) sbuf[w] = acc;
  __syncthreads();
  if (threadIdx.x == 0)
    loffp[t * 512 + blockIdx.x] = sbuf[0] + sbuf[1] + sbuf[2] + sbuf[3];
}

__global__ void fini(const float* __restrict__ loffp, const float* __restrict__ lv,
                     const float* __restrict__ yl, float* __restrict__ out) {
  int tid = threadIdx.x, w = tid >> 6, lane = tid & 63;
  float s = 0.f, s2 = 0.f;
  for (int i = tid; i < 2048; i += 256) s += loffp[i];
  for (int i = tid; i < 4096; i += 256) {
    float l = lv[i];
    float ym = 0.25f * (yl[i] + yl[4096 + i] + yl[8192 + i] + yl[12288 + i]);
    s2 += fmaxf(l, 0.f) - l * ym + log1pf(expf(-fabsf(l)));
  }
  s = wred(s); s2 = wred(s2);
  __shared__ float sb[4], sb2[4];
  if (lane == 0) { sb[w] = s; sb2[w] = s2; }
  __syncthreads();
  if (tid == 0) {
    out[16384] = (sb[0] + sb[1] + sb[2] + sb[3]) / (4.f * 2048.f * 16.f);
    out[16385] = (sb2[0] + sb2[1] + sb2[2] + sb2[3]) / 4096.f;
  }
}

__global__ void wsprobe(float marker, float* out) {
  if (threadIdx.x == 0) out[0] = marker;
}

// ---------------- launch ----------------
extern "C" void kernel_launch(void* const* d_in, const int* in_sizes, int n_in,
                              void* d_out, int out_size, void* d_ws, size_t ws_size,
                              hipStream_t stream) {
  const float* x_feature   = (const float*)d_in[0];
  const float* x_graph     = (const float*)d_in[1];
  const float* x_graph_inv = (const float*)d_in[2];
  const int*   temp_y      = (const int*)d_in[3];
  const float* is_leaf     = (const float*)d_in[4];
  const float* W_gcn       = (const float*)d_in[5];
  const float* b_gcn       = (const float*)d_in[6];
  const float* Wx_zr       = (const float*)d_in[7];
  const float* Wh_zr       = (const float*)d_in[8];
  const float* b_zr        = (const float*)d_in[9];
  const float* Wx_c        = (const float*)d_in[10];
  const float* Wh_c        = (const float*)d_in[11];
  const float* b_c         = (const float*)d_in[12];
  const float* h_vecs      = (const float*)d_in[13];
  const float* W_leaf      = (const float*)d_in[14];
  const float* b_leaf      = (const float*)d_in[15];
  const float* W_conv      = (const float*)d_in[16];
  const float* b_conv      = (const float*)d_in[17];
  float* out = (float*)d_out;
  (void)in_sizes; (void)n_in; (void)out_size;

  const size_t NEED = 156000000;  // ~149 MB; ws_size = 268 MB (R7 fill evidence)
  if (ws_size < NEED) {
    wsprobe<<<1, 64, 0, stream>>>(1000.f + (float)(ws_size >> 20), out);
    return;
  }

  char* ws = (char*)d_ws;
  size_t off = 0;
  auto alloc = [&](size_t bytes) -> void* {
    void* p = ws + off;
    off = (off + bytes + 255) & ~(size_t)255;
    return p;
  };
  bf16*   Whzrt = (bf16*)  alloc((size_t)1024 * 512 * 2);
  bf16*   Whct  = (bf16*)  alloc((size_t)512 * 512 * 2);
  bf16*   Wxzrt = (bf16*)  alloc((size_t)1024 * 512 * 2);
  bf16*   Wxct  = (bf16*)  alloc((size_t)512 * 512 * 2);
  bf16*   Wgt   = (bf16*)  alloc((size_t)256 * 128 * 2);
  bf16*   hfin  = (bf16*)  alloc((size_t)32768 * 512 * 2);  // 32 MB
  bf16*   xzrp  = (bf16*)  alloc((size_t)32768 * 1024 * 2); // 64 MB (bias folded)
  bf16*   xcp   = (bf16*)  alloc((size_t)32768 * 512 * 2);  // 32 MB (bias folded)
  bf16*   hsb   = (bf16*)  alloc((size_t)4096 * 512 * 2);
  bf16*   rhb   = (bf16*)  alloc((size_t)4096 * 512 * 2);
  __half* zh    = (__half*)alloc((size_t)4096 * 512 * 2);
  float*  lv    = (float*) alloc(4096 * 4);
  float*  hn    = (float*) alloc(4 * 512 * 4);
  float*  v     = (float*) alloc(4 * 512 * 4);
  float*  loffp = (float*) alloc(2048 * 4);
  bf16*   Htrb  = hfin;   // overlay: hfin dead after gemmx consumes it

  hipMemsetAsync(hsb, 0, (size_t)4096 * 512 * 2, stream);   // h0 = 0
  hipMemsetAsync(v, 0, 4 * 512 * 4, stream);

  prep<<<6272, 256, 0, stream>>>(Wh_zr, Wh_c, Wx_zr, Wx_c, W_gcn,
                                 Whzrt, Whct, Wxzrt, Wxct, Wgt);
  gcnk<<<dim3(256, 2, 2), 256, 0, stream>>>(x_graph, x_graph_inv, Wgt, b_gcn, hfin);
  gemmx<<<dim3(256, 12), 256, 0, stream>>>(hfin, Wxzrt, Wxct, b_zr, b_c, xzrp, xcp);

  // sequential GRU: 64x64 tiles, BK=128, 1024/512 blocks per launch
  for (int t = 0; t < 8; ++t) {
    const bf16* xz = xzrp + (size_t)t * 4096 * 1024;
    const bf16* xc = xcp + (size_t)t * 4096 * 512;
    gruk<<<dim3(64, 16), 256, 0, stream>>>(hsb, Whzrt, xz, 1024, 1, zh, rhb, hsb);
    gruk<<<dim3(64, 8), 256, 0, stream>>>(rhb, Whct, xc, 512, 2, zh, nullptr, hsb);
  }

  norm_lvec<<<1025, 256, 0, stream>>>(hsb, W_leaf, b_leaf, h_vecs, Htrb, lv, hn);
  htf<<<64, 512, 0, stream>>>(Htrb, x_feature, W_conv, b_conv, lv, v);
  attk<<<1024, 256, 0, stream>>>(Htrb, v, out);
  loff<<<dim3(512, 4), 256, 0, stream>>>(Htrb, hn, temp_y, loffp);
  fini<<<1, 256, 0, stream>>>(loffp, lv, is_leaf, out);
}